// Round 12
// baseline (1680.349 us; speedup 1.0000x reference)
//
#include <hip/hip_runtime.h>
#include <hip/hip_fp16.h>
#include <stdint.h>

// LSTM policy rollout, all-AGPR weights, wave-aligned rows, 1 barrier/step.
// 256 blocks x 512 threads (8 waves, 2 waves/SIMD, 256 regs/thread budget).
// Wave w owns h rows 2w,2w+1 fully: 6 gate rows x 4096 f16 = 192 AGPR slots
// (inline-asm "a" class, unspillable). No LDS weight reads at all.
// Sync: tagged {payload,epoch} u64 words at MALL scope (relaxed agent
// atomics, no fences/invalidates) + tagged LDS words for intra-block o/pp.
// Per step: dots -> lane0 h-update + immediate publish -> gather -> barrier.

#define HID    4096
#define CTX    1024
#define NSTEPS 256
#define NBLK   256
#define TPB    512
#define WAVES  8
#define HROWS  16
#define NCH    8           // column chunks of 512

typedef _Float16 h2 __attribute__((ext_vector_type(2)));

__device__ __forceinline__ float fdot2f(uint32_t a, uint32_t b, float c) {
#if __has_builtin(__builtin_amdgcn_fdot2)
  return __builtin_amdgcn_fdot2(__builtin_bit_cast(h2, a),
                                __builtin_bit_cast(h2, b), c, false);
#else
  h2 x = __builtin_bit_cast(h2, a), y = __builtin_bit_cast(h2, b);
  return c + (float)x[0]*(float)y[0] + (float)x[1]*(float)y[1];
#endif
}
__device__ __forceinline__ uint32_t pkf16(float x, float y) {
  h2 v; v[0] = (_Float16)x; v[1] = (_Float16)y;
  return __builtin_bit_cast(uint32_t, v);
}
__device__ __forceinline__ uint4 cvt8(const float* p) {
  return make_uint4(pkf16(p[0],p[1]), pkf16(p[2],p[3]),
                    pkf16(p[4],p[5]), pkf16(p[6],p[7]));
}
// AGPR residency (proven rounds 7-11).
__device__ __forceinline__ void agw(uint32_t &slot, uint32_t v) {
  asm volatile("v_accvgpr_write_b32 %0, %1" : "=a"(slot) : "v"(v));
}
__device__ __forceinline__ uint32_t agr(uint32_t slot) {
  uint32_t v;
  asm("v_accvgpr_read_b32 %0, %1" : "=v"(v) : "a"(slot));
  return v;
}
// MALL-coherent tagged exchange (global).
__device__ __forceinline__ void stT(uint64_t* p, uint32_t payload, uint32_t tag) {
  const uint64_t v = ((uint64_t)tag << 32) | (uint64_t)payload;
  __hip_atomic_store(p, v, __ATOMIC_RELAXED, __HIP_MEMORY_SCOPE_AGENT);
}
__device__ __forceinline__ uint64_t ldT(const uint64_t* p) {
  return __hip_atomic_load(p, __ATOMIC_RELAXED, __HIP_MEMORY_SCOPE_AGENT);
}
// LDS tagged exchange (workgroup scope).
__device__ __forceinline__ void stL(uint64_t* p, uint64_t v) {
  __hip_atomic_store(p, v, __ATOMIC_RELAXED, __HIP_MEMORY_SCOPE_WORKGROUP);
}
__device__ __forceinline__ uint64_t ldL(const uint64_t* p) {
  return __hip_atomic_load(p, __ATOMIC_RELAXED, __HIP_MEMORY_SCOPE_WORKGROUP);
}
// wave-uniform float -> SGPR
__device__ __forceinline__ float rfl(float x) {
  return __builtin_bit_cast(float,
      __builtin_amdgcn_readfirstlane(__builtin_bit_cast(int, x)));
}

__global__ __launch_bounds__(TPB, 2)
void lstm(const float* __restrict__ ctx, const float* __restrict__ u,
          const float* __restrict__ l1w, const float* __restrict__ l1b,
          const float* __restrict__ Wf,  const float* __restrict__ Wfb,
          const float* __restrict__ Wi,  const float* __restrict__ Wib,
          const float* __restrict__ Wc,  const float* __restrict__ Wcb,
          const float* __restrict__ Wow, const float* __restrict__ Wob,
          uint64_t* __restrict__ hh0, uint64_t* __restrict__ hh1,
          uint64_t* __restrict__ part0, uint64_t* __restrict__ part1,
          float* __restrict__ out)
{
  __shared__ uint4   zsh[2][HID/8];   // z f16x2, double-buffered, 16 KB
  __shared__ float    red[WAVES];
  __shared__ float    x0sh;
  __shared__ uint64_t osh;            // {epoch, f32 o}
  __shared__ uint64_t pp[WAVES];      // {epoch, f32 partial}

  const int tid  = threadIdx.x;
  const int b    = blockIdx.x;
  const int wv   = tid >> 6;
  const int lane = tid & 63;

  {
    uint32_t* z0 = (uint32_t*)&zsh[0][0];
    for (int i = tid; i < HID/2; i += TPB) z0[i] = 0u;
    if (tid == 0) osh = 0ull;
    if (tid < WAVES) pp[tid] = 0ull;
  }

  const int hr0 = b*HROWS + 2*wv;     // this wave's global h-row base
  const float* rp[6] = {
    Wf + (size_t)(hr0  )*4097, Wf + (size_t)(hr0+1)*4097,
    Wi + (size_t)(hr0  )*4097, Wi + (size_t)(hr0+1)*4097,
    Wc + (size_t)(hr0  )*4097, Wc + (size_t)(hr0+1)*4097 };

  // wave-uniform constants -> SGPRs
  const float bf0 = rfl(Wfb[hr0]), bf1 = rfl(Wfb[hr0+1]);
  const float bi0 = rfl(Wib[hr0]), bi1 = rfl(Wib[hr0+1]);
  const float bc0 = rfl(Wcb[hr0]), bc1 = rfl(Wcb[hr0+1]);
  const float xf0 = rfl(rp[0][HID]), xf1 = rfl(rp[1][HID]);
  const float xi0 = rfl(rp[2][HID]), xi1 = rfl(rp[3][HID]);
  const float xc0 = rfl(rp[4][HID]), xc1 = rfl(rp[5][HID]);
  const float wo0 = rfl(Wow[hr0]),  wo1 = rfl(Wow[hr0+1]);
  const float woxw = Wow[HID], wobv = Wob[0];

  // 6 gate rows -> 192 AGPR slots (f16x2 packed)
  uint32_t wreg[192];
  #pragma unroll
  for (int r = 0; r < 6; ++r) {
    #pragma unroll
    for (int c = 0; c < NCH; ++c) {
      const uint4 v = cvt8(rp[r] + c*512 + lane*8);
      agw(wreg[r*32+c*4+0], v.x);
      agw(wreg[r*32+c*4+1], v.y);
      agw(wreg[r*32+c*4+2], v.z);
      agw(wreg[r*32+c*4+3], v.w);
    }
  }

  // x0 = l1_w . context + l1_b (identical in every block); CTX == 2*TPB
  {
    float p = l1w[tid]*ctx[tid] + l1w[tid+TPB]*ctx[tid+TPB];
    #pragma unroll
    for (int off = 32; off; off >>= 1) p += __shfl_down(p, off, 64);
    __syncthreads();                   // covers zsh[0]/osh/pp init
    if (lane == 0) red[wv] = p;
    __syncthreads();
    if (tid == 0) {
      float s2 = 0.f;
      for (int w = 0; w < WAVES; ++w) s2 += red[w];
      x0sh = s2 + l1b[0];
    }
    __syncthreads();
  }
  float xcur = x0sh;
  float logp = 0.f;
  float ut = u[0];
  float cs0 = 0.f, cs1 = 0.f;

  for (int t = 0; t < NSTEPS; ++t) {
    // ---- wave 0: issue o-partial loads early (checked after dots) ----
    const uint64_t* prd = (t & 1) ? part0 : part1;
    uint64_t pv0 = 0, pv1 = 0, pv2 = 0, pv3 = 0;
    if (wv == 0 && t > 0) {
      pv0 = ldT(&prd[lane*4+0]); pv1 = ldT(&prd[lane*4+1]);
      pv2 = ldT(&prd[lane*4+2]); pv3 = ldT(&prd[lane*4+3]);
    }

    // ---- gate dots: 6 rows, all weights from AGPRs ----
    float a[6] = {0.f,0.f,0.f,0.f,0.f,0.f};
    const uint4* zb = zsh[t & 1];
    #pragma unroll
    for (int c = 0; c < NCH; ++c) {
      const uint4 zz = zb[c*64 + lane];
      const uint32_t za[4] = {zz.x, zz.y, zz.z, zz.w};
      #pragma unroll
      for (int r = 0; r < 6; ++r) {
        #pragma unroll
        for (int e = 0; e < 4; ++e)
          a[r] = fdot2f(agr(wreg[r*32+c*4+e]), za[e], a[r]);
      }
    }
    #pragma unroll
    for (int off = 32; off; off >>= 1) {
      #pragma unroll
      for (int r = 0; r < 6; ++r) a[r] += __shfl_down(a[r], off, 64);
    }

    // ---- wave 0: finish o, publish to LDS (tag t+1) ----
    if (wv == 0) {
      float ps = 0.f;
      if (t > 0) {
        const uint32_t tg = (uint32_t)t;
        while ((uint32_t)(pv0 >> 32) != tg) { __builtin_amdgcn_s_sleep(1); pv0 = ldT(&prd[lane*4+0]); }
        while ((uint32_t)(pv1 >> 32) != tg) { __builtin_amdgcn_s_sleep(1); pv1 = ldT(&prd[lane*4+1]); }
        while ((uint32_t)(pv2 >> 32) != tg) { __builtin_amdgcn_s_sleep(1); pv2 = ldT(&prd[lane*4+2]); }
        while ((uint32_t)(pv3 >> 32) != tg) { __builtin_amdgcn_s_sleep(1); pv3 = ldT(&prd[lane*4+3]); }
        const float q0 = __uint_as_float((uint32_t)pv0);
        const float q1 = __uint_as_float((uint32_t)pv1);
        const float q2 = __uint_as_float((uint32_t)pv2);
        const float q3 = __uint_as_float((uint32_t)pv3);
        ps = ((q0 + q1) + q2) + q3;
      }
      #pragma unroll
      for (int off = 32; off; off >>= 1) ps += __shfl_down(ps, off, 64);
      if (lane == 0) {
        const float opre = ps + woxw*xcur + wobv;
        const float o = 1.f / (1.f + expf(-opre));
        stL(&osh, ((uint64_t)(uint32_t)(t+1) << 32) | (uint64_t)__float_as_uint(o));
      }
    }

    // ---- lane 0 of each wave: h update + immediate publish ----
    uint64_t* hw = (t & 1) ? hh1 : hh0;
    uint64_t* pw = (t & 1) ? part1 : part0;
    if (lane == 0) {
      uint64_t ov = ldL(&osh);
      while ((uint32_t)(ov >> 32) != (uint32_t)(t+1)) {
        __builtin_amdgcn_s_sleep(1); ov = ldL(&osh);
      }
      const float o = __uint_as_float((uint32_t)ov);
      const float s = (ut < o) ? 1.f : 0.f;
      const float pf0 = a[0] + xf0*xcur + bf0;
      const float pf1 = a[1] + xf1*xcur + bf1;
      const float pi0 = a[2] + xi0*xcur + bi0;
      const float pi1 = a[3] + xi1*xcur + bi1;
      const float pc0 = a[4] + xc0*xcur + bc0;
      const float pc1 = a[5] + xc1*xcur + bc1;
      const float ff0 = 1.f/(1.f+expf(-pf0)), ff1 = 1.f/(1.f+expf(-pf1));
      const float ii0 = 1.f/(1.f+expf(-pi0)), ii1 = 1.f/(1.f+expf(-pi1));
      const float cc0 = tanhf(pc0), cc1 = tanhf(pc1);
      cs0 = ff0*cs0 + ii0*cc0;
      cs1 = ff1*cs1 + ii1*cc1;
      const float hv0 = o*tanhf(cs0), hv1 = o*tanhf(cs1);
      stT(&hw[b*8 + wv], pkf16(hv0, hv1), (uint32_t)(t+1));
      const float ppv = wo0*hv0 + wo1*hv1;
      stL(&pp[wv], ((uint64_t)(uint32_t)(t+1) << 32) | (uint64_t)__float_as_uint(ppv));
      xcur = s;
      if (b == 0 && wv == 0) {
        logp += (s != 0.f) ? logf(o) : logf(1.f - o);
        out[t] = s;
      }
    }

    // ---- wave 0: collect 8 LDS partials, publish block partial ----
    if (wv == 0) {
      float v = 0.f;
      if (lane < WAVES) {
        uint64_t e = ldL(&pp[lane]);
        while ((uint32_t)(e >> 32) != (uint32_t)(t+1)) {
          __builtin_amdgcn_s_sleep(1); e = ldL(&pp[lane]);
        }
        v = __uint_as_float((uint32_t)e);
      }
      v += __shfl_down(v, 4, 64);
      v += __shfl_down(v, 2, 64);
      v += __shfl_down(v, 1, 64);
      if (lane == 0) stT(&pw[b], __float_as_uint(v), (uint32_t)(t+1));
    }

    if (t + 1 < NSTEPS) {
      // ---- gather z(t+1): poll tagged words (4 per thread) ----
      const uint64_t* hr = (t & 1) ? hh1 : hh0;
      const uint32_t tg = (uint32_t)(t+1);
      uint64_t v0 = ldT(&hr[tid]);
      uint64_t v1 = ldT(&hr[tid +   TPB]);
      uint64_t v2 = ldT(&hr[tid + 2*TPB]);
      uint64_t v3 = ldT(&hr[tid + 3*TPB]);
      while ((uint32_t)(v0 >> 32) != tg) { __builtin_amdgcn_s_sleep(1); v0 = ldT(&hr[tid]); }
      while ((uint32_t)(v1 >> 32) != tg) { __builtin_amdgcn_s_sleep(1); v1 = ldT(&hr[tid +   TPB]); }
      while ((uint32_t)(v2 >> 32) != tg) { __builtin_amdgcn_s_sleep(1); v2 = ldT(&hr[tid + 2*TPB]); }
      while ((uint32_t)(v3 >> 32) != tg) { __builtin_amdgcn_s_sleep(1); v3 = ldT(&hr[tid + 3*TPB]); }
      uint32_t* zn = (uint32_t*)&zsh[(t+1) & 1][0];
      zn[tid]         = (uint32_t)v0;
      zn[tid +   TPB] = (uint32_t)v1;
      zn[tid + 2*TPB] = (uint32_t)v2;
      zn[tid + 3*TPB] = (uint32_t)v3;
      ut = u[t+1];
      __syncthreads();
    }
  }
  if (b == 0 && tid == 0) out[NSTEPS] = logp;
}

extern "C" void kernel_launch(void* const* d_in, const int* in_sizes, int n_in,
                              void* d_out, int out_size, void* d_ws, size_t ws_size,
                              hipStream_t stream) {
  const float* ctx = (const float*)d_in[0];
  const float* u   = (const float*)d_in[1];
  const float* l1w = (const float*)d_in[2];
  const float* l1b = (const float*)d_in[3];
  const float* Wf  = (const float*)d_in[4];
  const float* Wfb = (const float*)d_in[5];
  const float* Wi  = (const float*)d_in[6];
  const float* Wib = (const float*)d_in[7];
  const float* Wc  = (const float*)d_in[8];
  const float* Wcb = (const float*)d_in[9];
  const float* Wow = (const float*)d_in[10];
  const float* Wob = (const float*)d_in[11];
  float* out = (float*)d_out;

  char* ws = (char*)d_ws;
  uint64_t* part0 = (uint64_t*)(ws + 4096);            // 256*8B
  uint64_t* part1 = (uint64_t*)(ws + 8192);
  uint64_t* hh0   = (uint64_t*)(ws + 12288);           // 2048*8B = 16 KB
  uint64_t* hh1   = (uint64_t*)(ws + 12288 + 16384);
  // zero all tags each launch (epochs 1..256; 0 == invalid)
  (void)hipMemsetAsync(ws + 4096, 0, 40960, stream);

  lstm<<<NBLK, TPB, 0, stream>>>(ctx,u,l1w,l1b,Wf,Wfb,Wi,Wib,Wc,Wcb,Wow,Wob,
                                 hh0,hh1,part0,part1,out);
}